// Round 5
// baseline (272.482 us; speedup 1.0000x reference)
//
#include <hip/hip_runtime.h>
#include <hip/hip_bf16.h>
#include <math.h>

// MHA: B=2,S=2048,E=1024,H=16,Dk=64. fp32 in/out, bf16 MFMA internally.
// 1. cvt_w: Wq,Wk,Wv,Wo fp32 -> bf16 (once)
// 2. qkv_gemm (z): x @ W^T + b -> Qw,Kw [B][H][S][Dk], Vtw [B][H][Dk][S]
//    128x128 tile, BK=64, swizzled LDS, W via global_load_lds
// 3. attn: flash, S^T-MFMA (packed bf16 P round-trip), no-max softmax -> Xw
// 4. fin_gemm: Xw @ Wo^T + bo -> out fp32

constexpr int Sn = 2048;
constexpr int En = 1024;
constexpr int Hn = 16;
constexpr int Dk = 64;
constexpr int Kn = 1024;
constexpr size_t WSZ = 1048576;   // 1024*1024 weight elems
constexpr size_t TSZ = 4194304;   // B*H*S*Dk tensor elems
constexpr int PST = 72;           // Ps row stride (bf16 elems)

typedef __bf16 bf16x8 __attribute__((ext_vector_type(8)));
typedef float  f32x4  __attribute__((ext_vector_type(4)));

union U16 { uint4 u; bf16x8 v; __hip_bfloat16 h[8]; };
union U8  { uint2 u; __hip_bfloat162 h2[2]; __hip_bfloat16 h[4]; };

__device__ inline U16 cvt8f(const float* __restrict__ p) {
    float4 a = *(const float4*)p;
    float4 b = *(const float4*)(p + 4);
    U16 r;
    r.h[0] = __float2bfloat16(a.x); r.h[1] = __float2bfloat16(a.y);
    r.h[2] = __float2bfloat16(a.z); r.h[3] = __float2bfloat16(a.w);
    r.h[4] = __float2bfloat16(b.x); r.h[5] = __float2bfloat16(b.y);
    r.h[6] = __float2bfloat16(b.z); r.h[7] = __float2bfloat16(b.w);
    return r;
}

__device__ inline void gload16(const __hip_bfloat16* g, __hip_bfloat16* l) {
    __builtin_amdgcn_global_load_lds(
        (const __attribute__((address_space(1))) void*)g,
        (__attribute__((address_space(3))) void*)l, 16, 0, 0);
}

// Stage ROWS x 64 bf16 tile via global_load_lds, XOR-swizzled:
// LDS granule p of row r holds global granule p^(r&7). Dest is lane-contiguous.
template<int ROWS, int NW>
__device__ inline void stage_tile(const __hip_bfloat16* __restrict__ src, int ld,
                                  __hip_bfloat16* lds, int w, int lane) {
    int l8 = lane >> 3;
    int g = (lane & 7) ^ (l8 & 7);
    #pragma unroll
    for (int j = 0; j < ROWS / (8 * NW); ++j) {
        int c = j * NW + w;
        gload16(src + (size_t)(c * 8 + l8) * ld + g * 8, lds + c * 512);
    }
}

// ---------------- weight convert ----------------
__global__ __launch_bounds__(256)
void cvt_w(const float* __restrict__ w0, const float* __restrict__ w1,
           const float* __restrict__ w2, const float* __restrict__ w3,
           __hip_bfloat16* __restrict__ dst)
{
    int y = blockIdx.y;
    const float* src = (y == 0) ? w0 : (y == 1) ? w1 : (y == 2) ? w2 : w3;
    size_t i = ((size_t)blockIdx.x * 256 + threadIdx.x) * 8;
    U16 r = cvt8f(src + i);
    *(uint4*)&dst[(size_t)y * WSZ + i] = r.u;
}

// ---------------- QKV projection GEMM ----------------
// 128x128 tile, BK=64, 4 waves each 64x64 (4x4 frags of 16x16).
__global__ __launch_bounds__(256)
void qkv_gemm(const float* __restrict__ xq, const float* __restrict__ xk,
              const float* __restrict__ xv, const __hip_bfloat16* __restrict__ Wbf,
              const float* __restrict__ bq, const float* __restrict__ bk,
              const float* __restrict__ bv,
              __hip_bfloat16* __restrict__ Qw, __hip_bfloat16* __restrict__ Kw,
              __hip_bfloat16* __restrict__ Vtw)
{
    __shared__ __align__(16) __hip_bfloat16 As[128 * 64];
    __shared__ __align__(16) __hip_bfloat16 Bs[128 * 64];

    const int tid = threadIdx.x, w = tid >> 6, lane = tid & 63;
    const int l15 = lane & 15, lg = lane >> 4, l7 = lane & 7;
    const int z = blockIdx.z;
    const float* A    = (z == 0) ? xq : (z == 1) ? xk : xv;
    const float* bias = (z == 0) ? bq : (z == 1) ? bk : bv;
    const __hip_bfloat16* W = Wbf + (size_t)z * WSZ;
    const int blockM = blockIdx.x * 128, blockN = blockIdx.y * 128;
    const int wm = (w & 1) * 64, wn = (w >> 1) * 64;

    const int arow = tid >> 1, acb = (tid & 1) * 4;   // A-stage: 32 fp32/thread
    const int coff0 = (lg ^ l7) * 8;
    const int coff1 = ((4 + lg) ^ l7) * 8;

    f32x4 acc[4][4];
    #pragma unroll
    for (int i = 0; i < 4; ++i)
        #pragma unroll
        for (int j = 0; j < 4; ++j) acc[i][j] = {0.f, 0.f, 0.f, 0.f};

    for (int k0 = 0; k0 < Kn; k0 += 64) {
        {   // A: fp32 load + cvt + swizzled store (4 granules/thread)
            const float* ap = A + (size_t)(blockM + arow) * Kn + k0 + acb * 8;
            int s7 = arow & 7;
            #pragma unroll
            for (int g = 0; g < 4; ++g) {
                U16 r = cvt8f(ap + g * 8);
                *(uint4*)&As[arow * 64 + (((acb + g) ^ s7) * 8)] = r.u;
            }
        }
        stage_tile<128, 4>(W + (size_t)blockN * Kn + k0, Kn, Bs, w, lane);
        __syncthreads();

        U16 af[4][2], bf[4][2];
        #pragma unroll
        for (int mt = 0; mt < 4; ++mt) {
            int r = (wm + mt * 16 + l15) * 64;
            af[mt][0].u = *(const uint4*)&As[r + coff0];
            af[mt][1].u = *(const uint4*)&As[r + coff1];
        }
        #pragma unroll
        for (int nt = 0; nt < 4; ++nt) {
            int r = (wn + nt * 16 + l15) * 64;
            bf[nt][0].u = *(const uint4*)&Bs[r + coff0];
            bf[nt][1].u = *(const uint4*)&Bs[r + coff1];
        }
        #pragma unroll
        for (int mt = 0; mt < 4; ++mt)
            #pragma unroll
            for (int nt = 0; nt < 4; ++nt) {
                acc[mt][nt] = __builtin_amdgcn_mfma_f32_16x16x32_bf16(af[mt][0].v, bf[nt][0].v, acc[mt][nt], 0, 0, 0);
                acc[mt][nt] = __builtin_amdgcn_mfma_f32_16x16x32_bf16(af[mt][1].v, bf[nt][1].v, acc[mt][nt], 0, 0, 0);
            }
        __syncthreads();
    }

    // epilogue. C/D: col=l15, row=lg*4+i
    #pragma unroll
    for (int nt = 0; nt < 4; ++nt) {
        int n = blockN + wn + nt * 16 + l15;
        float bvn = bias[n];
        int h_ = n >> 6, d_ = n & 63;
        #pragma unroll
        for (int mt = 0; mt < 4; ++mt) {
            int m0 = blockM + wm + mt * 16 + lg * 4;
            int b_ = m0 >> 11, s_ = m0 & (Sn - 1);
            if (z == 2) {
                U8 pk;
                #pragma unroll
                for (int i = 0; i < 4; ++i) pk.h[i] = __float2bfloat16(acc[mt][nt][i] + bvn);
                *(uint2*)&Vtw[(((size_t)b_ * Hn + h_) * Dk + d_) * Sn + s_] = pk.u;
            } else {
                __hip_bfloat16* D = (z == 0) ? Qw : Kw;
                #pragma unroll
                for (int i = 0; i < 4; ++i)
                    D[(((size_t)b_ * Hn + h_) * Sn + s_ + i) * Dk + d_] =
                        __float2bfloat16(acc[mt][nt][i] + bvn);
            }
        }
    }
}

// ---------------- final GEMM: Xw(bf16) @ Wo^T + bo -> fp32 ----------------
__global__ __launch_bounds__(256)
void fin_gemm(const __hip_bfloat16* __restrict__ A, const __hip_bfloat16* __restrict__ W,
              const float* __restrict__ bias, float* __restrict__ out)
{
    __shared__ __align__(16) __hip_bfloat16 As[128 * 64];
    __shared__ __align__(16) __hip_bfloat16 Bs[128 * 64];

    const int tid = threadIdx.x, w = tid >> 6, lane = tid & 63;
    const int l15 = lane & 15, lg = lane >> 4, l7 = lane & 7;
    const int blockM = blockIdx.x * 128, blockN = blockIdx.y * 128;
    const int wm = (w & 1) * 64, wn = (w >> 1) * 64;
    const int coff0 = (lg ^ l7) * 8;
    const int coff1 = ((4 + lg) ^ l7) * 8;

    f32x4 acc[4][4];
    #pragma unroll
    for (int i = 0; i < 4; ++i)
        #pragma unroll
        for (int j = 0; j < 4; ++j) acc[i][j] = {0.f, 0.f, 0.f, 0.f};

    for (int k0 = 0; k0 < Kn; k0 += 64) {
        stage_tile<128, 4>(A + (size_t)blockM * Kn + k0, Kn, As, w, lane);
        stage_tile<128, 4>(W + (size_t)blockN * Kn + k0, Kn, Bs, w, lane);
        __syncthreads();

        U16 af[4][2], bf[4][2];
        #pragma unroll
        for (int mt = 0; mt < 4; ++mt) {
            int r = (wm + mt * 16 + l15) * 64;
            af[mt][0].u = *(const uint4*)&As[r + coff0];
            af[mt][1].u = *(const uint4*)&As[r + coff1];
        }
        #pragma unroll
        for (int nt = 0; nt < 4; ++nt) {
            int r = (wn + nt * 16 + l15) * 64;
            bf[nt][0].u = *(const uint4*)&Bs[r + coff0];
            bf[nt][1].u = *(const uint4*)&Bs[r + coff1];
        }
        #pragma unroll
        for (int mt = 0; mt < 4; ++mt)
            #pragma unroll
            for (int nt = 0; nt < 4; ++nt) {
                acc[mt][nt] = __builtin_amdgcn_mfma_f32_16x16x32_bf16(af[mt][0].v, bf[nt][0].v, acc[mt][nt], 0, 0, 0);
                acc[mt][nt] = __builtin_amdgcn_mfma_f32_16x16x32_bf16(af[mt][1].v, bf[nt][1].v, acc[mt][nt], 0, 0, 0);
            }
        __syncthreads();
    }

    #pragma unroll
    for (int nt = 0; nt < 4; ++nt) {
        int n = blockN + wn + nt * 16 + l15;
        float bvn = bias[n];
        #pragma unroll
        for (int mt = 0; mt < 4; ++mt) {
            int m0 = blockM + wm + mt * 16 + lg * 4;
            #pragma unroll
            for (int i = 0; i < 4; ++i)
                out[(size_t)(m0 + i) * Kn + n] = acc[mt][nt][i] + bvn;
        }
    }
}

// ---------------- flash attention (S^T MFMA, no-max softmax) ----------------
// 256 thr (4 waves), 128 queries/block (32/wave), 64-key tiles.
// S^T = K·Q^T: A=K-frag, B=Q-frag -> C row=key(lg*4+i), col=q(l15):
//   packed b64 bf16 P stores into Ps[q][key]; PV reads Ps rows as A-frags.
__global__ __launch_bounds__(256)
void attn(const __hip_bfloat16* __restrict__ Q, const __hip_bfloat16* __restrict__ K,
          const __hip_bfloat16* __restrict__ Vt, __hip_bfloat16* __restrict__ X)
{
    __shared__ __align__(16) __hip_bfloat16 Ks[64 * 64];
    __shared__ __align__(16) __hip_bfloat16 Vts[64 * 64];
    __shared__ __align__(16) __hip_bfloat16 Ps[128 * PST];

    const int bh = blockIdx.y, q0 = blockIdx.x * 128;
    const int tid = threadIdx.x, w = tid >> 6, lane = tid & 63;
    const int l15 = lane & 15, lg = lane >> 4, l7 = lane & 7;
    const int coff0 = (lg ^ l7) * 8;
    const int coff1 = ((4 + lg) ^ l7) * 8;

    const __hip_bfloat16* Qb = Q  + (size_t)bh * Sn * Dk;
    const __hip_bfloat16* Kb = K  + (size_t)bh * Sn * Dk;
    const __hip_bfloat16* Vb = Vt + (size_t)bh * Dk * Sn;

    // Q B-frags in registers: rows q0 + w*32 + qt*16 + l15
    U16 aq[2][2];
    #pragma unroll
    for (int qt = 0; qt < 2; ++qt) {
        const __hip_bfloat16* qp = Qb + (size_t)(q0 + w * 32 + qt * 16 + l15) * Dk + lg * 8;
        aq[qt][0].u = *(const uint4*)qp;
        aq[qt][1].u = *(const uint4*)(qp + 32);
    }

    f32x4 o[2][4];          // [qt][dt], C: row=q(lg*4+i), col=d(l15)
    float lpart[2];         // per-qt partial l for query l15 (this lane's keys)
    #pragma unroll
    for (int qt = 0; qt < 2; ++qt) {
        lpart[qt] = 0.f;
        #pragma unroll
        for (int dt = 0; dt < 4; ++dt) o[qt][dt] = {0.f, 0.f, 0.f, 0.f};
    }

    __hip_bfloat16* Pw = Ps + (w * 32) * PST;   // wave-private 32 rows

    for (int k0 = 0; k0 < Sn; k0 += 64) {
        stage_tile<64, 4>(Kb + (size_t)k0 * Dk, Dk, Ks, w, lane);   // [key][d]
        stage_tile<64, 4>(Vb + k0, Sn, Vts, w, lane);               // [d][key]
        __syncthreads();

        // S^T: A = K-frags, B = Q-frags
        U16 kf[4][2];
        #pragma unroll
        for (int kt = 0; kt < 4; ++kt) {
            int r = (kt * 16 + l15) * 64;
            kf[kt][0].u = *(const uint4*)&Ks[r + coff0];
            kf[kt][1].u = *(const uint4*)&Ks[r + coff1];
        }
        #pragma unroll
        for (int kt = 0; kt < 4; ++kt)
            #pragma unroll
            for (int qt = 0; qt < 2; ++qt) {
                f32x4 s = {0.f, 0.f, 0.f, 0.f};
                s = __builtin_amdgcn_mfma_f32_16x16x32_bf16(kf[kt][0].v, aq[qt][0].v, s, 0, 0, 0);
                s = __builtin_amdgcn_mfma_f32_16x16x32_bf16(kf[kt][1].v, aq[qt][1].v, s, 0, 0, 0);
                // P = exp(s/8); rows = keys kt*16+lg*4+i, col = q l15
                float p0 = __expf(s[0] * 0.125f), p1 = __expf(s[1] * 0.125f);
                float p2 = __expf(s[2] * 0.125f), p3 = __expf(s[3] * 0.125f);
                lpart[qt] += (p0 + p1) + (p2 + p3);
                U8 pk;
                pk.h2[0] = __float22bfloat162_rn({p0, p1});
                pk.h2[1] = __float22bfloat162_rn({p2, p3});
                *(uint2*)&Pw[(qt * 16 + l15) * PST + kt * 16 + lg * 4] = pk.u;
            }

        // PV: A = P rows (q=l15), B = V^T rows (d=l15)
        U16 pf[2][2], vf[4][2];
        #pragma unroll
        for (int qt = 0; qt < 2; ++qt) {
            const __hip_bfloat16* pr = &Pw[(qt * 16 + l15) * PST + lg * 8];
            pf[qt][0].u = *(const uint4*)pr;
            pf[qt][1].u = *(const uint4*)(pr + 32);
        }
        #pragma unroll
        for (int dt = 0; dt < 4; ++dt) {
            int r = (dt * 16 + l15) * 64;
            vf[dt][0].u = *(const uint4*)&Vts[r + coff0];
            vf[dt][1].u = *(const uint4*)&Vts[r + coff1];
        }
        #pragma unroll
        for (int qt = 0; qt < 2; ++qt)
            #pragma unroll
            for (int dt = 0; dt < 4; ++dt) {
                o[qt][dt] = __builtin_amdgcn_mfma_f32_16x16x32_bf16(pf[qt][0].v, vf[dt][0].v, o[qt][dt], 0, 0, 0);
                o[qt][dt] = __builtin_amdgcn_mfma_f32_16x16x32_bf16(pf[qt][1].v, vf[dt][1].v, o[qt][dt], 0, 0, 0);
            }
        __syncthreads();
    }

    // l: reduce across the 4 lg-groups (lanes sharing l15), then fan out
    float linv[2][4];
    #pragma unroll
    for (int qt = 0; qt < 2; ++qt) {
        float v = lpart[qt];
        v += __shfl_xor(v, 16, 64);
        v += __shfl_xor(v, 32, 64);
        #pragma unroll
        for (int i = 0; i < 4; ++i)
            linv[qt][i] = 1.f / __shfl(v, lg * 4 + i, 16);
    }

    int b_ = bh >> 4, h_ = bh & (Hn - 1);
    #pragma unroll
    for (int qt = 0; qt < 2; ++qt)
        #pragma unroll
        for (int i = 0; i < 4; ++i) {
            int sr = q0 + w * 32 + qt * 16 + lg * 4 + i;
            __hip_bfloat16* xp = X + ((size_t)(b_ * Sn + sr)) * En + h_ * Dk + l15;
            #pragma unroll
            for (int dt = 0; dt < 4; ++dt)
                xp[dt * 16] = __float2bfloat16(o[qt][dt][i] * linv[qt][i]);
        }
}

extern "C" void kernel_launch(void* const* d_in, const int* in_sizes, int n_in,
                              void* d_out, int out_size, void* d_ws, size_t ws_size,
                              hipStream_t stream)
{
    const float* query = (const float*)d_in[0];
    const float* key   = (const float*)d_in[1];
    const float* value = (const float*)d_in[2];
    const float* Wq = (const float*)d_in[3];
    const float* bq = (const float*)d_in[4];
    const float* Wk = (const float*)d_in[5];
    const float* bk = (const float*)d_in[6];
    const float* Wv = (const float*)d_in[7];
    const float* bv = (const float*)d_in[8];
    const float* Wo = (const float*)d_in[9];
    const float* bo = (const float*)d_in[10];
    float* out = (float*)d_out;

    __hip_bfloat16* Wbf = (__hip_bfloat16*)d_ws;
    __hip_bfloat16* Qw  = Wbf + 4 * WSZ;
    __hip_bfloat16* Kw  = Qw + TSZ;
    __hip_bfloat16* Vtw = Kw + TSZ;
    __hip_bfloat16* Xw  = Vtw + TSZ;

    cvt_w<<<dim3(512, 4), 256, 0, stream>>>(Wq, Wk, Wv, Wo, Wbf);
    qkv_gemm<<<dim3(32, 8, 3), 256, 0, stream>>>(query, key, value, Wbf,
                                                 bq, bk, bv, Qw, Kw, Vtw);
    attn<<<dim3(Sn / 128, 32), 256, 0, stream>>>(Qw, Kw, Vtw, Xw);
    fin_gemm<<<dim3(32, 8), 256, 0, stream>>>(Xw, Wbf + 3 * WSZ, bo, out);
}

// Round 6
// 245.457 us; speedup vs baseline: 1.1101x; 1.1101x over previous
//
#include <hip/hip_runtime.h>
#include <hip/hip_bf16.h>
#include <math.h>

// MHA: B=2,S=2048,E=1024,H=16,Dk=64. fp32 in/out, bf16 MFMA internally.
// cvt_w: 4 weights fp32->bf16. cvt_x: one activation fp32->bf16 into shared buf.
// gemm64<MODE>: 64x128 tile, BK=64, both operands via swizzled global_load_lds.
//   MODE 0: fp32 out + bias; 1: bf16 [B][H][S][Dk]; 2: bf16 [B][H][Dk][S].
// attn: S^T-MFMA flash, no-max softmax, ping-pong K/V LDS (1 barrier/iter).

constexpr int Sn = 2048;
constexpr int En = 1024;
constexpr int Hn = 16;
constexpr int Dk = 64;
constexpr int Kn = 1024;
constexpr size_t WSZ = 1048576;   // 1024*1024
constexpr size_t TSZ = 4194304;   // 4096*1024
constexpr int PST = 72;           // Ps row stride

typedef __bf16 bf16x8 __attribute__((ext_vector_type(8)));
typedef float  f32x4  __attribute__((ext_vector_type(4)));

union U16 { uint4 u; bf16x8 v; __hip_bfloat16 h[8]; };
union U8  { uint2 u; __hip_bfloat162 h2[2]; __hip_bfloat16 h[4]; };

__device__ inline U16 cvt8f(const float* __restrict__ p) {
    float4 a = *(const float4*)p;
    float4 b = *(const float4*)(p + 4);
    U16 r;
    r.h[0] = __float2bfloat16(a.x); r.h[1] = __float2bfloat16(a.y);
    r.h[2] = __float2bfloat16(a.z); r.h[3] = __float2bfloat16(a.w);
    r.h[4] = __float2bfloat16(b.x); r.h[5] = __float2bfloat16(b.y);
    r.h[6] = __float2bfloat16(b.z); r.h[7] = __float2bfloat16(b.w);
    return r;
}

__device__ inline void gload16(const __hip_bfloat16* g, __hip_bfloat16* l) {
    __builtin_amdgcn_global_load_lds(
        (const __attribute__((address_space(1))) void*)g,
        (__attribute__((address_space(3))) void*)l, 16, 0, 0);
}

// Stage ROWS x 64 bf16 tile via global_load_lds, XOR-swizzled:
// LDS granule p of row r holds global granule p^(r&7). Dest lane-contiguous.
template<int ROWS, int NW>
__device__ inline void stage_tile(const __hip_bfloat16* __restrict__ src, int ld,
                                  __hip_bfloat16* lds, int w, int lane) {
    int l8 = lane >> 3;
    int g = (lane & 7) ^ (l8 & 7);
    #pragma unroll
    for (int j = 0; j < ROWS / (8 * NW); ++j) {
        int c = j * NW + w;
        gload16(src + (size_t)(c * 8 + l8) * ld + g * 8, lds + c * 512);
    }
}

// ---------------- converts ----------------
__global__ __launch_bounds__(256)
void cvt_w(const float* __restrict__ w0, const float* __restrict__ w1,
           const float* __restrict__ w2, const float* __restrict__ w3,
           __hip_bfloat16* __restrict__ dst)
{
    int y = blockIdx.y;
    const float* src = (y == 0) ? w0 : (y == 1) ? w1 : (y == 2) ? w2 : w3;
    size_t i = ((size_t)blockIdx.x * 256 + threadIdx.x) * 8;
    U16 r = cvt8f(src + i);
    *(uint4*)&dst[(size_t)y * WSZ + i] = r.u;
}

__global__ __launch_bounds__(256)
void cvt_x(const float* __restrict__ src, __hip_bfloat16* __restrict__ dst)
{
    size_t i = ((size_t)blockIdx.x * 256 + threadIdx.x) * 8;
    U16 r = cvt8f(src + i);
    *(uint4*)&dst[i] = r.u;
}

// ---------------- GEMM: C[m][n] = sum_k A[m][k]*W[n][k] (+bias) ----------------
// 64(M) x 128(N) tile, BK=64, 4 waves each 32x64 (2x4 frags).
template<int MODE>
__global__ __launch_bounds__(256)
void gemm64(const __hip_bfloat16* __restrict__ A, const __hip_bfloat16* __restrict__ W,
            const float* __restrict__ bias, void* __restrict__ outp)
{
    __shared__ __align__(16) __hip_bfloat16 As[64 * 64];
    __shared__ __align__(16) __hip_bfloat16 Bs[128 * 64];

    const int tid = threadIdx.x, w = tid >> 6, lane = tid & 63;
    const int l15 = lane & 15, lg = lane >> 4, l7 = lane & 7;
    const int blockM = blockIdx.x * 64, blockN = blockIdx.y * 128;
    const int wm = (w & 1) * 32, wn = (w >> 1) * 64;
    const int coff0 = (lg ^ l7) * 8;
    const int coff1 = ((4 + lg) ^ l7) * 8;

    f32x4 acc[2][4];
    #pragma unroll
    for (int i = 0; i < 2; ++i)
        #pragma unroll
        for (int j = 0; j < 4; ++j) acc[i][j] = {0.f, 0.f, 0.f, 0.f};

    for (int k0 = 0; k0 < Kn; k0 += 64) {
        stage_tile<64, 4>(A + (size_t)blockM * Kn + k0, Kn, As, w, lane);
        stage_tile<128, 4>(W + (size_t)blockN * Kn + k0, Kn, Bs, w, lane);
        __syncthreads();

        U16 af[2][2], bf[4][2];
        #pragma unroll
        for (int mt = 0; mt < 2; ++mt) {
            int r = (wm + mt * 16 + l15) * 64;
            af[mt][0].u = *(const uint4*)&As[r + coff0];
            af[mt][1].u = *(const uint4*)&As[r + coff1];
        }
        #pragma unroll
        for (int nt = 0; nt < 4; ++nt) {
            int r = (wn + nt * 16 + l15) * 64;
            bf[nt][0].u = *(const uint4*)&Bs[r + coff0];
            bf[nt][1].u = *(const uint4*)&Bs[r + coff1];
        }
        #pragma unroll
        for (int mt = 0; mt < 2; ++mt)
            #pragma unroll
            for (int nt = 0; nt < 4; ++nt) {
                acc[mt][nt] = __builtin_amdgcn_mfma_f32_16x16x32_bf16(af[mt][0].v, bf[nt][0].v, acc[mt][nt], 0, 0, 0);
                acc[mt][nt] = __builtin_amdgcn_mfma_f32_16x16x32_bf16(af[mt][1].v, bf[nt][1].v, acc[mt][nt], 0, 0, 0);
            }
        __syncthreads();
    }

    // epilogue. C/D: col=l15, row=lg*4+i
    #pragma unroll
    for (int nt = 0; nt < 4; ++nt) {
        int n = blockN + wn + nt * 16 + l15;
        float bvn = bias[n];
        int h_ = n >> 6, d_ = n & 63;
        #pragma unroll
        for (int mt = 0; mt < 2; ++mt) {
            int m0 = blockM + wm + mt * 16 + lg * 4;
            if constexpr (MODE == 0) {
                float* out = (float*)outp;
                #pragma unroll
                for (int i = 0; i < 4; ++i)
                    out[(size_t)(m0 + i) * Kn + n] = acc[mt][nt][i] + bvn;
            } else if constexpr (MODE == 1) {
                __hip_bfloat16* out = (__hip_bfloat16*)outp;
                int b_ = m0 >> 11, s_ = m0 & (Sn - 1);
                #pragma unroll
                for (int i = 0; i < 4; ++i)
                    out[(((size_t)b_ * Hn + h_) * Sn + s_ + i) * Dk + d_] =
                        __float2bfloat16(acc[mt][nt][i] + bvn);
            } else {
                __hip_bfloat16* out = (__hip_bfloat16*)outp;
                int b_ = m0 >> 11, s_ = m0 & (Sn - 1);
                U8 pk;
                #pragma unroll
                for (int i = 0; i < 4; ++i) pk.h[i] = __float2bfloat16(acc[mt][nt][i] + bvn);
                *(uint2*)&out[(((size_t)b_ * Hn + h_) * Dk + d_) * Sn + s_] = pk.u;
            }
        }
    }
}

// ---------------- flash attention (S^T MFMA, ping-pong K/V) ----------------
// 256 thr (4 waves), 128 q/block (32/wave), 64-key tiles, 1 barrier/iter.
__global__ __launch_bounds__(256)
void attn(const __hip_bfloat16* __restrict__ Q, const __hip_bfloat16* __restrict__ K,
          const __hip_bfloat16* __restrict__ Vt, __hip_bfloat16* __restrict__ X)
{
    __shared__ __align__(16) __hip_bfloat16 Ks[2][64 * 64];
    __shared__ __align__(16) __hip_bfloat16 Vts[2][64 * 64];
    __shared__ __align__(16) __hip_bfloat16 Ps[128 * PST];

    const int bh = blockIdx.y, q0 = blockIdx.x * 128;
    const int tid = threadIdx.x, w = tid >> 6, lane = tid & 63;
    const int l15 = lane & 15, lg = lane >> 4, l7 = lane & 7;
    const int coff0 = (lg ^ l7) * 8;
    const int coff1 = ((4 + lg) ^ l7) * 8;

    const __hip_bfloat16* Qb = Q  + (size_t)bh * Sn * Dk;
    const __hip_bfloat16* Kb = K  + (size_t)bh * Sn * Dk;
    const __hip_bfloat16* Vb = Vt + (size_t)bh * Dk * Sn;

    U16 aq[2][2];
    #pragma unroll
    for (int qt = 0; qt < 2; ++qt) {
        const __hip_bfloat16* qp = Qb + (size_t)(q0 + w * 32 + qt * 16 + l15) * Dk + lg * 8;
        aq[qt][0].u = *(const uint4*)qp;
        aq[qt][1].u = *(const uint4*)(qp + 32);
    }

    f32x4 o[2][4];
    float lpart[2];
    #pragma unroll
    for (int qt = 0; qt < 2; ++qt) {
        lpart[qt] = 0.f;
        #pragma unroll
        for (int dt = 0; dt < 4; ++dt) o[qt][dt] = {0.f, 0.f, 0.f, 0.f};
    }

    __hip_bfloat16* Pw = Ps + (w * 32) * PST;

    stage_tile<64, 4>(Kb, Dk, Ks[0], w, lane);
    stage_tile<64, 4>(Vb, Sn, Vts[0], w, lane);

    for (int t = 0; t < Sn / 64; ++t) {
        __syncthreads();   // tile t's loads drained; prior reads of buf[t&1^1] done
        const int cur = t & 1;
        if (t + 1 < Sn / 64) {
            stage_tile<64, 4>(Kb + (size_t)(t + 1) * 64 * Dk, Dk, Ks[cur ^ 1], w, lane);
            stage_tile<64, 4>(Vb + (t + 1) * 64, Sn, Vts[cur ^ 1], w, lane);
        }

        // S^T = K·Q^T
        U16 kf[4][2];
        #pragma unroll
        for (int kt = 0; kt < 4; ++kt) {
            int r = (kt * 16 + l15) * 64;
            kf[kt][0].u = *(const uint4*)&Ks[cur][r + coff0];
            kf[kt][1].u = *(const uint4*)&Ks[cur][r + coff1];
        }
        #pragma unroll
        for (int kt = 0; kt < 4; ++kt)
            #pragma unroll
            for (int qt = 0; qt < 2; ++qt) {
                f32x4 s = {0.f, 0.f, 0.f, 0.f};
                s = __builtin_amdgcn_mfma_f32_16x16x32_bf16(kf[kt][0].v, aq[qt][0].v, s, 0, 0, 0);
                s = __builtin_amdgcn_mfma_f32_16x16x32_bf16(kf[kt][1].v, aq[qt][1].v, s, 0, 0, 0);
                float p0 = __expf(s[0] * 0.125f), p1 = __expf(s[1] * 0.125f);
                float p2 = __expf(s[2] * 0.125f), p3 = __expf(s[3] * 0.125f);
                lpart[qt] += (p0 + p1) + (p2 + p3);
                U8 pk;
                pk.h2[0] = __float22bfloat162_rn({p0, p1});
                pk.h2[1] = __float22bfloat162_rn({p2, p3});
                *(uint2*)&Pw[(qt * 16 + l15) * PST + kt * 16 + lg * 4] = pk.u;
            }

        // PV (P rows wave-private: no barrier needed)
        U16 pf[2][2], vf[4][2];
        #pragma unroll
        for (int qt = 0; qt < 2; ++qt) {
            const __hip_bfloat16* pr = &Pw[(qt * 16 + l15) * PST + lg * 8];
            pf[qt][0].u = *(const uint4*)pr;
            pf[qt][1].u = *(const uint4*)(pr + 32);
        }
        #pragma unroll
        for (int dt = 0; dt < 4; ++dt) {
            int r = (dt * 16 + l15) * 64;
            vf[dt][0].u = *(const uint4*)&Vts[cur][r + coff0];
            vf[dt][1].u = *(const uint4*)&Vts[cur][r + coff1];
        }
        #pragma unroll
        for (int qt = 0; qt < 2; ++qt)
            #pragma unroll
            for (int dt = 0; dt < 4; ++dt) {
                o[qt][dt] = __builtin_amdgcn_mfma_f32_16x16x32_bf16(pf[qt][0].v, vf[dt][0].v, o[qt][dt], 0, 0, 0);
                o[qt][dt] = __builtin_amdgcn_mfma_f32_16x16x32_bf16(pf[qt][1].v, vf[dt][1].v, o[qt][dt], 0, 0, 0);
            }
    }

    float linv[2][4];
    #pragma unroll
    for (int qt = 0; qt < 2; ++qt) {
        float v = lpart[qt];
        v += __shfl_xor(v, 16, 64);
        v += __shfl_xor(v, 32, 64);
        #pragma unroll
        for (int i = 0; i < 4; ++i)
            linv[qt][i] = 1.f / __shfl(v, lg * 4 + i, 16);
    }

    int b_ = bh >> 4, h_ = bh & (Hn - 1);
    #pragma unroll
    for (int qt = 0; qt < 2; ++qt)
        #pragma unroll
        for (int i = 0; i < 4; ++i) {
            int sr = q0 + w * 32 + qt * 16 + lg * 4 + i;
            __hip_bfloat16* xp = X + ((size_t)(b_ * Sn + sr)) * En + h_ * Dk + l15;
            #pragma unroll
            for (int dt = 0; dt < 4; ++dt)
                xp[dt * 16] = __float2bfloat16(o[qt][dt][i] * linv[qt][i]);
        }
}

extern "C" void kernel_launch(void* const* d_in, const int* in_sizes, int n_in,
                              void* d_out, int out_size, void* d_ws, size_t ws_size,
                              hipStream_t stream)
{
    const float* query = (const float*)d_in[0];
    const float* key   = (const float*)d_in[1];
    const float* value = (const float*)d_in[2];
    const float* Wq = (const float*)d_in[3];
    const float* bq = (const float*)d_in[4];
    const float* Wk = (const float*)d_in[5];
    const float* bk = (const float*)d_in[6];
    const float* Wv = (const float*)d_in[7];
    const float* bv = (const float*)d_in[8];
    const float* Wo = (const float*)d_in[9];
    const float* bo = (const float*)d_in[10];
    float* out = (float*)d_out;

    // ws (bf16 elems): xbuf[4M] | Wbf[4M] | Qw[4M] | Kw[4M] | Vtw[4M] = 40 MB.
    // Xw (attn out) aliases xbuf (dead after last projection).
    __hip_bfloat16* xbuf = (__hip_bfloat16*)d_ws;
    __hip_bfloat16* Wbf  = xbuf + TSZ;
    __hip_bfloat16* Qw   = Wbf + 4 * WSZ;
    __hip_bfloat16* Kw   = Qw + TSZ;
    __hip_bfloat16* Vtw  = Kw + TSZ;
    __hip_bfloat16* Xw   = xbuf;

    dim3 ggrid(64, 8);   // 4096/64 x 1024/128

    cvt_w<<<dim3(512, 4), 256, 0, stream>>>(Wq, Wk, Wv, Wo, Wbf);
    cvt_x<<<2048, 256, 0, stream>>>(query, xbuf);
    gemm64<1><<<ggrid, 256, 0, stream>>>(xbuf, Wbf, bq, Qw);
    cvt_x<<<2048, 256, 0, stream>>>(key, xbuf);
    gemm64<1><<<ggrid, 256, 0, stream>>>(xbuf, Wbf + WSZ, bk, Kw);
    cvt_x<<<2048, 256, 0, stream>>>(value, xbuf);
    gemm64<2><<<ggrid, 256, 0, stream>>>(xbuf, Wbf + 2 * WSZ, bv, Vtw);
    attn<<<dim3(Sn / 128, 32), 256, 0, stream>>>(Qw, Kw, Vtw, Xw);
    gemm64<0><<<ggrid, 256, 0, stream>>>(Xw, Wbf + 3 * WSZ, bo, out);
}